// Round 4
// baseline (186.780 us; speedup 1.0000x reference)
//
#include <hip/hip_runtime.h>
#include <hip/hip_bf16.h>

#define N_ROWS 8192
#define D_DIM  1024
#define DELTA  0.1f
#define EPSF   1e-8f

#define BM 256
#define BN 256
#define BK 64
#define NT (D_DIM / BK)   // 16 K-tiles

typedef __attribute__((ext_vector_type(8))) short bf16x8;
typedef __attribute__((ext_vector_type(4))) float f32x4;

__device__ inline unsigned short f2bf(float f) {
    __hip_bfloat16 h = __float2bfloat16(f);
    return *reinterpret_cast<unsigned short*>(&h);
}

// One block per row: compute xx, yy, xy; write normalized bf16 rows + pos.
__global__ __launch_bounds__(256) void norm_kernel(
    const float* __restrict__ X, const float* __restrict__ Y,
    unsigned short* __restrict__ Xn, unsigned short* __restrict__ Yn,
    float* __restrict__ pos)
{
    const int row = blockIdx.x;
    const int t = threadIdx.x;            // 256 threads, 4 f32 each = 1024
    const float4 xv = reinterpret_cast<const float4*>(X + (size_t)row * D_DIM)[t];
    const float4 yv = reinterpret_cast<const float4*>(Y + (size_t)row * D_DIM)[t];

    float xx = xv.x*xv.x + xv.y*xv.y + xv.z*xv.z + xv.w*xv.w;
    float yy = yv.x*yv.x + yv.y*yv.y + yv.z*yv.z + yv.w*yv.w;
    float xy = xv.x*yv.x + xv.y*yv.y + xv.z*yv.z + xv.w*yv.w;

    #pragma unroll
    for (int off = 32; off > 0; off >>= 1) {
        xx += __shfl_xor(xx, off);
        yy += __shfl_xor(yy, off);
        xy += __shfl_xor(xy, off);
    }
    __shared__ float red[12];
    const int wid = t >> 6, lane = t & 63;
    if (lane == 0) { red[wid] = xx; red[4 + wid] = yy; red[8 + wid] = xy; }
    __syncthreads();
    xx = red[0] + red[1] + red[2] + red[3];
    yy = red[4] + red[5] + red[6] + red[7];
    xy = red[8] + red[9] + red[10] + red[11];

    const float rnx = 1.0f / fmaxf(sqrtf(xx), EPSF);
    const float rny = 1.0f / fmaxf(sqrtf(yy), EPSF);
    if (t == 0) pos[row] = xy * rnx * rny;

    ushort4 ox, oy;
    ox.x = f2bf(xv.x * rnx); ox.y = f2bf(xv.y * rnx);
    ox.z = f2bf(xv.z * rnx); ox.w = f2bf(xv.w * rnx);
    oy.x = f2bf(yv.x * rny); oy.y = f2bf(yv.y * rny);
    oy.z = f2bf(yv.z * rny); oy.w = f2bf(yv.w * rny);
    reinterpret_cast<ushort4*>(Xn + (size_t)row * D_DIM)[t] = ox;
    reinterpret_cast<ushort4*>(Yn + (size_t)row * D_DIM)[t] = oy;
}

#define GLDS16(gptr, lptr) \
    __builtin_amdgcn_global_load_lds((const __attribute__((address_space(1))) void*)(gptr), \
                                     (__attribute__((address_space(3))) void*)(lptr), 16, 0, 0)

// Swizzled LDS read: logical chunk lc (8 bf16 = 16B) of row -> physical chunk lc^(row&7).
__device__ inline bf16x8 ldf(const unsigned short* base, int row, int lc) {
    const int pc = lc ^ (row & 7);
    return *reinterpret_cast<const bf16x8*>(base + row * BK + pc * 8);
}

// One 8KB staging unit (64 rows): per-thread one 16B gload_lds.
// LDS dest linear; swizzle applied on the GLOBAL source chunk (both-sides rule).
#define STAGE1(dst, gbase, kk, j) { \
    const unsigned short* g_ = (gbase) + (size_t)((j) * 8 + srow) * D_DIM + (kk) + schunk * 8; \
    GLDS16(g_, (dst) + (j) * 512); }

#define LOAD_A(g) { _Pragma("unroll") for (int mi = 0; mi < 4; ++mi) { \
    const int r = wm * 128 + ((g) * 4 + mi) * 16 + (lane & 15); \
    afr[mi][0] = ldf(a, r, (lane >> 4)); \
    afr[mi][1] = ldf(a, r, 4 + (lane >> 4)); } }

#define LOAD_B_H(h) { _Pragma("unroll") for (int nj = 0; nj < 2; ++nj) { \
    const int cc = wn * 64 + ((h) * 2 + nj) * 16 + (lane & 15); \
    bfr[(h)*2+nj][0] = ldf(b, cc, (lane >> 4)); \
    bfr[(h)*2+nj][1] = ldf(b, cc, 4 + (lane >> 4)); } }

#define MFMA_Q(g, h) { _Pragma("unroll") for (int mi = 0; mi < 4; ++mi) { \
    _Pragma("unroll") for (int nj = 0; nj < 2; ++nj) { \
        acc[(g)*4+mi][(h)*2+nj] = __builtin_amdgcn_mfma_f32_16x16x32_bf16(afr[mi][0], bfr[(h)*2+nj][0], acc[(g)*4+mi][(h)*2+nj], 0, 0, 0); \
        acc[(g)*4+mi][(h)*2+nj] = __builtin_amdgcn_mfma_f32_16x16x32_bf16(afr[mi][1], bfr[(h)*2+nj][1], acc[(g)*4+mi][(h)*2+nj], 0, 0, 0); } } }

#define BARRIER() __builtin_amdgcn_s_barrier()
#define SB0() __builtin_amdgcn_sched_barrier(0)
#define WAIT_LGKM0() { asm volatile("s_waitcnt lgkmcnt(0)" ::: "memory"); __builtin_amdgcn_sched_barrier(0); }
#define PRIO1() __builtin_amdgcn_s_setprio(1)
#define PRIO0() __builtin_amdgcn_s_setprio(0)

// S = Xn * Yn^T 256x256 tile; 4-phase interleaved schedule, counted vmcnt(6),
// prefetch distance 2 with region-wise in-place restage; fused hinge + sum.
__global__ __launch_bounds__(512, 2) void gemm_loss_kernel(
    const unsigned short* __restrict__ A,   // Xn [N][D] bf16
    const unsigned short* __restrict__ B,   // Yn [N][D] bf16
    const float* __restrict__ pos,
    float* __restrict__ out)
{
    __shared__ __align__(16) unsigned short sA[2][BM * BK];  // 64 KB
    __shared__ __align__(16) unsigned short sB[2][BN * BK];  // 64 KB
    __shared__ float sPos[BM];
    __shared__ float redW[8];

    // XCD-aware swizzle (1024 blocks, 1024 % 8 == 0 -> bijective)
    const int nwg = gridDim.x;
    const int bid = blockIdx.x;
    const int cpx = nwg >> 3;
    const int swz = (bid & 7) * cpx + (bid >> 3);
    const int row0 = (swz >> 5) * BM;   // 32 tiles per dim
    const int col0 = (swz & 31) * BN;

    const int tid = threadIdx.x;
    const int lane = tid & 63;
    const int wid = tid >> 6;        // 8 waves: 2M x 4N
    const int wm = wid >> 2;         // rows [wm*128, +128)
    const int wn = wid & 3;          // cols [wn*64, +64)

    const int srow = lane >> 3;                     // 0..7
    const int schunk = (lane & 7) ^ srow;           // pre-swizzled global chunk
    const unsigned short* Ab = A + (size_t)row0 * D_DIM;
    const unsigned short* Bb = B + (size_t)col0 * D_DIM;

    f32x4 acc[8][4] = {};
    bf16x8 afr[4][2], bfr[4][2];

    // prologue: tile0 fully (8 loads), then tile1's first 6 in steady-state
    // region order (A{0-63,128-191}, B{0-127}, A{64-127,192-255}).
    STAGE1(&sA[0][0], Ab, 0, wid);       STAGE1(&sA[0][0], Ab, 0, 8 + wid);
    STAGE1(&sA[0][0], Ab, 0, 16 + wid);  STAGE1(&sA[0][0], Ab, 0, 24 + wid);
    STAGE1(&sB[0][0], Bb, 0, wid);       STAGE1(&sB[0][0], Bb, 0, 8 + wid);
    STAGE1(&sB[0][0], Bb, 0, 16 + wid);  STAGE1(&sB[0][0], Bb, 0, 24 + wid);
    STAGE1(&sA[1][0], Ab, BK, wid);      STAGE1(&sA[1][0], Ab, BK, 16 + wid);
    STAGE1(&sB[1][0], Bb, BK, wid);      STAGE1(&sB[1][0], Bb, BK, 8 + wid);
    STAGE1(&sA[1][0], Ab, BK, 8 + wid);  STAGE1(&sA[1][0], Ab, BK, 24 + wid);

    for (int kt = 0; kt < NT; ++kt) {
        const int c = kt & 1, cn = c ^ 1;
        // boundary: tile kt's 8 stage loads (all but newest 6) complete
        if (kt == NT - 1) { asm volatile("s_waitcnt vmcnt(0)" ::: "memory"); }
        else              { asm volatile("s_waitcnt vmcnt(6)" ::: "memory"); }
        BARRIER(); SB0();

        const unsigned short* a = &sA[c][0];
        const unsigned short* b = &sB[c][0];
        const int k1 = (kt + 1) * BK, k2 = (kt + 2) * BK;

        // P0: read A(0)+B(0); stage tile kt+1's B rows 128-255 (other buffer)
        LOAD_A(0); LOAD_B_H(0);
        if (kt + 1 < NT) { STAGE1(&sB[cn][0], Bb, k1, 16 + wid); STAGE1(&sB[cn][0], Bb, k1, 24 + wid); }
        SB0(); BARRIER(); WAIT_LGKM0();
        PRIO1(); MFMA_Q(0, 0); PRIO0();
        SB0(); BARRIER();

        // P1: read B(1); stage tile kt+2's A rows {0-63,128-191} (freed in P0)
        LOAD_B_H(1);
        if (kt + 2 < NT) { STAGE1(&sA[c][0], Ab, k2, wid); STAGE1(&sA[c][0], Ab, k2, 16 + wid); }
        SB0(); BARRIER(); WAIT_LGKM0();
        PRIO1(); MFMA_Q(0, 1); PRIO0();
        SB0(); BARRIER();

        // P2: read A(1); stage tile kt+2's B rows 0-127 (B freed in P1)
        LOAD_A(1);
        if (kt + 2 < NT) { STAGE1(&sB[c][0], Bb, k2, wid); STAGE1(&sB[c][0], Bb, k2, 8 + wid); }
        SB0(); BARRIER(); WAIT_LGKM0();
        PRIO1(); MFMA_Q(1, 1); PRIO0();
        SB0(); BARRIER();

        // P3: stage tile kt+2's A rows {64-127,192-255} (freed in P2); pure MFMA
        if (kt + 2 < NT) { STAGE1(&sA[c][0], Ab, k2, 8 + wid); STAGE1(&sA[c][0], Ab, k2, 24 + wid); }
        PRIO1(); MFMA_Q(1, 0); PRIO0();
    }

    // pos staged only now (keeps K-loop vmcnt accounting pure)
    if (tid < BM) sPos[tid] = pos[row0 + tid];
    __syncthreads();

    // epilogue: hinge = max(0, DELTA - pos[i] + S[i][j]), skip diagonal, sum
    float local = 0.0f;
    #pragma unroll
    for (int mi = 0; mi < 8; ++mi) {
        #pragma unroll
        for (int jj = 0; jj < 4; ++jj) {
            const int lr = wm * 128 + mi * 16 + (lane >> 4) * 4 + jj;
            const int gr = row0 + lr;
            const float basev = DELTA - sPos[lr];
            #pragma unroll
            for (int nj = 0; nj < 4; ++nj) {
                const int gc = col0 + wn * 64 + nj * 16 + (lane & 15);
                float h = basev + acc[mi][nj][jj];
                h = fmaxf(h, 0.0f);
                if (gr == gc) h = 0.0f;
                local += h;
            }
        }
    }
    #pragma unroll
    for (int off = 32; off > 0; off >>= 1) local += __shfl_xor(local, off);
    if (lane == 0) redW[wid] = local;
    __syncthreads();
    if (tid == 0) {
        float s = 0.0f;
        #pragma unroll
        for (int w = 0; w < 8; ++w) s += redW[w];
        atomicAdd(out, s);
    }
}

extern "C" void kernel_launch(void* const* d_in, const int* in_sizes, int n_in,
                              void* d_out, int out_size, void* d_ws, size_t ws_size,
                              hipStream_t stream) {
    const float* X = (const float*)d_in[0];
    const float* Y = (const float*)d_in[1];
    float* out = (float*)d_out;

    unsigned short* Xn = (unsigned short*)d_ws;
    unsigned short* Yn = Xn + (size_t)N_ROWS * D_DIM;
    float* pos = (float*)(Yn + (size_t)N_ROWS * D_DIM);

    hipMemsetAsync(d_out, 0, sizeof(float), stream);
    norm_kernel<<<N_ROWS, 256, 0, stream>>>(X, Y, Xn, Yn, pos);
    const int ntiles = (N_ROWS / BM) * (N_ROWS / BN);   // 1024
    gemm_loss_kernel<<<dim3(ntiles), 512, 0, stream>>>(Xn, Yn, pos, out);
}

// Round 5
// 95.872 us; speedup vs baseline: 1.9482x; 1.9482x over previous
//
#include <hip/hip_runtime.h>
#include <hip/hip_bf16.h>

#define N_ROWS 8192
#define D_DIM  1024           // elements per row; fp8 row = 1024 bytes
#define DELTA  0.1f
#define EPSF   1e-8f

#define BM 256
#define BN 256
#define BKB 128               // K-tile bytes (fp8 elems) per row
#define NT (D_DIM / BKB)      // 8 K-tiles

typedef __attribute__((ext_vector_type(4))) int   i32x4;
typedef __attribute__((ext_vector_type(8))) int   i32x8;
typedef __attribute__((ext_vector_type(4))) float f32x4;

// One block per row: compute xx, yy, xy; write normalized fp8(e4m3) rows + fp32 pos.
__global__ __launch_bounds__(256) void norm_kernel(
    const float* __restrict__ X, const float* __restrict__ Y,
    unsigned int* __restrict__ Xn, unsigned int* __restrict__ Yn,   // fp8 rows as u32x256
    float* __restrict__ pos)
{
    const int row = blockIdx.x;
    const int t = threadIdx.x;            // 256 threads, 4 f32 each = 1024
    const float4 xv = reinterpret_cast<const float4*>(X + (size_t)row * D_DIM)[t];
    const float4 yv = reinterpret_cast<const float4*>(Y + (size_t)row * D_DIM)[t];

    float xx = xv.x*xv.x + xv.y*xv.y + xv.z*xv.z + xv.w*xv.w;
    float yy = yv.x*yv.x + yv.y*yv.y + yv.z*yv.z + yv.w*yv.w;
    float xy = xv.x*yv.x + xv.y*yv.y + xv.z*yv.z + xv.w*yv.w;

    #pragma unroll
    for (int off = 32; off > 0; off >>= 1) {
        xx += __shfl_xor(xx, off);
        yy += __shfl_xor(yy, off);
        xy += __shfl_xor(xy, off);
    }
    __shared__ float red[12];
    const int wid = t >> 6, lane = t & 63;
    if (lane == 0) { red[wid] = xx; red[4 + wid] = yy; red[8 + wid] = xy; }
    __syncthreads();
    xx = red[0] + red[1] + red[2] + red[3];
    yy = red[4] + red[5] + red[6] + red[7];
    xy = red[8] + red[9] + red[10] + red[11];

    const float rnx = 1.0f / fmaxf(sqrtf(xx), EPSF);
    const float rny = 1.0f / fmaxf(sqrtf(yy), EPSF);
    if (t == 0) pos[row] = xy * rnx * rny;

    // pack 4 normalized f32 -> 4 e4m3 bytes (HW RNE conversion)
    int wx = __builtin_amdgcn_cvt_pk_fp8_f32(xv.x * rnx, xv.y * rnx, 0, false);
    wx     = __builtin_amdgcn_cvt_pk_fp8_f32(xv.z * rnx, xv.w * rnx, wx, true);
    int wy = __builtin_amdgcn_cvt_pk_fp8_f32(yv.x * rny, yv.y * rny, 0, false);
    wy     = __builtin_amdgcn_cvt_pk_fp8_f32(yv.z * rny, yv.w * rny, wy, true);
    Xn[(size_t)row * 256 + t] = (unsigned int)wx;
    Yn[(size_t)row * 256 + t] = (unsigned int)wy;
}

#define GLDS16(gptr, lptr) \
    __builtin_amdgcn_global_load_lds((const __attribute__((address_space(1))) void*)(gptr), \
                                     (__attribute__((address_space(3))) void*)(lptr), 16, 0, 0)

// Swizzled 16B-chunk read: logical chunk lc of row -> physical chunk lc^(row&7).
// 32B fragment = chunks {c0, c0+1}, each independently swizzled (write side matches).
__device__ inline i32x8 ldfrag32(const unsigned char* base, int row, int c0) {
    const int p0 = (c0) ^ (row & 7);
    const int p1 = (c0 + 1) ^ (row & 7);
    const i32x4 u = *reinterpret_cast<const i32x4*>(base + row * BKB + p0 * 16);
    const i32x4 v = *reinterpret_cast<const i32x4*>(base + row * BKB + p1 * 16);
    i32x8 r;
    r[0] = u[0]; r[1] = u[1]; r[2] = u[2]; r[3] = u[3];
    r[4] = v[0]; r[5] = v[1]; r[6] = v[2]; r[7] = v[3];
    return r;
}

// One 1KB staging unit (8 rows x 128B): per-thread one 16B gload_lds.
// LDS dest linear (lane*16 = row srow, chunk lane&7); global source chunk
// pre-swizzled so LDS[row][p] = G[row][p ^ (row&7)].
#define STAGE1(dst, gbase, kk, j) { \
    const unsigned char* g_ = (gbase) + (size_t)((j) * 8 + srow) * D_DIM + (kk) + schunk * 16; \
    GLDS16(g_, (dst) + (j) * 1024); }

#define STAGE_P(dst, gbase, kk) { \
    STAGE1(dst, gbase, kk, wid); STAGE1(dst, gbase, kk, 8 + wid); \
    STAGE1(dst, gbase, kk, 16 + wid); STAGE1(dst, gbase, kk, 24 + wid); }

#define LOAD_A_G(g) { _Pragma("unroll") for (int mi = 0; mi < 4; ++mi) { \
    const int r = wm * 128 + ((g) * 4 + mi) * 16 + (lane & 15); \
    af[mi] = ldfrag32(a, r, (lane >> 4) * 2); } }

#define LOAD_B_ALL() { _Pragma("unroll") for (int nj = 0; nj < 4; ++nj) { \
    const int cc = wn * 64 + nj * 16 + (lane & 15); \
    bf[nj] = ldfrag32(b, cc, (lane >> 4) * 2); } }

// 16 mfma_scale per half; unit scales (0x7F = e8m0 exponent 127 = 1.0)
#define MFMA_H(g) { _Pragma("unroll") for (int mi = 0; mi < 4; ++mi) { \
    _Pragma("unroll") for (int nj = 0; nj < 4; ++nj) { \
        acc[(g)*4+mi][nj] = __builtin_amdgcn_mfma_scale_f32_16x16x128_f8f6f4( \
            af[mi], bf[nj], acc[(g)*4+mi][nj], 0, 0, 0, 0x7F7F7F7F, 0, 0x7F7F7F7F); } } }

// S = Xn * Yn^T 256x256 fp8 tile; counted-vmcnt pipeline (prefetch distance 2,
// in-place buffer reuse after whole-tile register fetch); fused hinge + sum.
__global__ __launch_bounds__(512, 2) void gemm_loss_kernel(
    const unsigned char* __restrict__ A,   // Xn [N][D] fp8 e4m3
    const unsigned char* __restrict__ B,   // Yn [N][D] fp8 e4m3
    const float* __restrict__ pos,
    float* __restrict__ out)
{
    __shared__ __align__(16) unsigned char sA[2][BM * BKB];  // 64 KB
    __shared__ __align__(16) unsigned char sB[2][BN * BKB];  // 64 KB
    __shared__ float sPos[BM];
    __shared__ float redW[8];

    // XCD-aware swizzle (1024 blocks, 1024 % 8 == 0 -> bijective)
    const int nwg = gridDim.x;
    const int bid = blockIdx.x;
    const int cpx = nwg >> 3;
    const int swz = (bid & 7) * cpx + (bid >> 3);
    const int row0 = (swz >> 5) * BM;   // 32 tiles per dim
    const int col0 = (swz & 31) * BN;

    const int tid = threadIdx.x;
    const int lane = tid & 63;
    const int wid = tid >> 6;        // 8 waves: 2M x 4N
    const int wm = wid >> 2;         // rows [wm*128, +128)
    const int wn = wid & 3;          // cols [wn*64, +64)

    const int srow = lane >> 3;                     // 0..7
    const int schunk = (lane & 7) ^ srow;           // pre-swizzled global chunk
    const unsigned char* Ab = A + (size_t)row0 * D_DIM;
    const unsigned char* Bb = B + (size_t)col0 * D_DIM;

    f32x4 acc[8][4] = {};
    i32x8 af[4], bf[4];

    // prologue: stage tiles 0 and 1 (16 loads/thread in flight)
    STAGE_P(&sA[0][0], Ab, 0);
    STAGE_P(&sB[0][0], Bb, 0);
    STAGE_P(&sA[1][0], Ab, BKB);
    STAGE_P(&sB[1][0], Bb, BKB);

    for (int kt = 0; kt < NT; ++kt) {
        const int c = kt & 1;
        // counted wait: tile kt's 8 loads (oldest) complete; kt+1's stay in flight
        if (kt == NT - 1) { asm volatile("s_waitcnt vmcnt(0)" ::: "memory"); }
        else              { asm volatile("s_waitcnt vmcnt(8)" ::: "memory"); }
        __builtin_amdgcn_s_barrier();
        __builtin_amdgcn_sched_barrier(0);

        const unsigned char* a = &sA[c][0];
        const unsigned char* b = &sB[c][0];

        LOAD_B_ALL();
        LOAD_A_G(0);
        __builtin_amdgcn_s_setprio(1);
        MFMA_H(0);
        __builtin_amdgcn_s_setprio(0);
        LOAD_A_G(1);
        // whole buffer consumed by every wave -> safe to restage in place
        asm volatile("s_waitcnt lgkmcnt(0)" ::: "memory");
        __builtin_amdgcn_s_barrier();
        __builtin_amdgcn_sched_barrier(0);
        if (kt + 2 < NT) {
            STAGE_P(&sA[c][0], Ab, (kt + 2) * BKB);
            STAGE_P(&sB[c][0], Bb, (kt + 2) * BKB);
        }
        __builtin_amdgcn_s_setprio(1);
        MFMA_H(1);
        __builtin_amdgcn_s_setprio(0);
    }

    // pos staged after the K-loop (keeps in-loop vmcnt accounting pure)
    if (tid < BM) sPos[tid] = pos[row0 + tid];
    __syncthreads();

    // epilogue: hinge = max(0, DELTA - pos[i] + S[i][j]), skip diagonal, sum
    float local = 0.0f;
    #pragma unroll
    for (int mi = 0; mi < 8; ++mi) {
        #pragma unroll
        for (int jj = 0; jj < 4; ++jj) {
            const int lr = wm * 128 + mi * 16 + (lane >> 4) * 4 + jj;
            const int gr = row0 + lr;
            const float basev = DELTA - sPos[lr];
            #pragma unroll
            for (int nj = 0; nj < 4; ++nj) {
                const int gc = col0 + wn * 64 + nj * 16 + (lane & 15);
                float h = basev + acc[mi][nj][jj];
                h = fmaxf(h, 0.0f);
                if (gr == gc) h = 0.0f;
                local += h;
            }
        }
    }
    #pragma unroll
    for (int off = 32; off > 0; off >>= 1) local += __shfl_xor(local, off);
    if (lane == 0) redW[wid] = local;
    __syncthreads();
    if (tid == 0) {
        float s = 0.0f;
        #pragma unroll
        for (int w = 0; w < 8; ++w) s += redW[w];
        atomicAdd(out, s);
    }
}

extern "C" void kernel_launch(void* const* d_in, const int* in_sizes, int n_in,
                              void* d_out, int out_size, void* d_ws, size_t ws_size,
                              hipStream_t stream) {
    const float* X = (const float*)d_in[0];
    const float* Y = (const float*)d_in[1];
    float* out = (float*)d_out;

    unsigned char* Xn = (unsigned char*)d_ws;                        // 8 MB fp8
    unsigned char* Yn = Xn + (size_t)N_ROWS * D_DIM;                 // 8 MB fp8
    float* pos = (float*)(Yn + (size_t)N_ROWS * D_DIM);              // 32 KB

    hipMemsetAsync(d_out, 0, sizeof(float), stream);
    norm_kernel<<<N_ROWS, 256, 0, stream>>>(X, Y, (unsigned int*)Xn, (unsigned int*)Yn, pos);
    const int ntiles = (N_ROWS / BM) * (N_ROWS / BN);   // 1024
    gemm_loss_kernel<<<dim3(ntiles), 512, 0, stream>>>(Xn, Yn, pos, out);
}